// Round 6
// baseline (449.961 us; speedup 1.0000x reference)
//
#include <hip/hip_runtime.h>
#include <math.h>

#define DIM 1024
#define HEADS 16
#define HEAD_DIM 64
#define HIDDEN 4096
#define NSEQ 1024
#define BATCH 4
#define TOKENS (BATCH * NSEQ)
#define EPS 1e-5f

typedef __bf16 bf16;
typedef __bf16 bf16x4 __attribute__((ext_vector_type(4)));
typedef __bf16 bf16x8 __attribute__((ext_vector_type(8)));
typedef float f32x4 __attribute__((ext_vector_type(4)));

#define AS1 __attribute__((address_space(1)))
#define AS3 __attribute__((address_space(3)))

#define CVT_QUADS 3145728   // (3M+1M+4M+4M)/4 total weight quads
#define CVT_BLOCKS 12288    // CVT_QUADS/256

// ---------------- prep: fused weight-convert + LN1 ----------------
__global__ __launch_bounds__(256) void prep_kernel(const float* __restrict__ x,
                                                   const float* __restrict__ g,
                                                   const float* __restrict__ bb,
                                                   bf16* __restrict__ h,
                                                   const float* __restrict__ s0,
                                                   const float* __restrict__ s1,
                                                   const float* __restrict__ s2,
                                                   const float* __restrict__ s3,
                                                   bf16* __restrict__ d0,
                                                   bf16* __restrict__ d1,
                                                   bf16* __restrict__ d2,
                                                   bf16* __restrict__ d3) {
    const int blk = blockIdx.x;
    const int tid = threadIdx.x;
    if (blk < CVT_BLOCKS) {
        size_t q = (size_t)blk * 256 + tid;
        const float* s;
        bf16* d;
        if (q < 786432) { s = s0; d = d0; }
        else if (q < 786432 + 262144) { q -= 786432; s = s1; d = d1; }
        else if (q < 786432 + 262144 + 1048576) { q -= 786432 + 262144; s = s2; d = d2; }
        else { q -= 786432 + 262144 + 1048576; s = s3; d = d3; }
        const float4 v = *(const float4*)(s + q * 4);
        bf16x4 o = {(bf16)v.x, (bf16)v.y, (bf16)v.z, (bf16)v.w};
        *(bf16x4*)(d + q * 4) = o;
        return;
    }
    // LayerNorm token
    const int t = blk - CVT_BLOCKS;
    const float* row = x + (size_t)t * DIM;
    float v[4];
    float s1v = 0.f, s2v = 0.f;
#pragma unroll
    for (int i = 0; i < 4; i++) {
        v[i] = row[tid + i * 256];
        s1v += v[i];
        s2v += v[i] * v[i];
    }
    __shared__ float w1[4], w2[4];
#pragma unroll
    for (int off = 32; off > 0; off >>= 1) {
        s1v += __shfl_down(s1v, off, 64);
        s2v += __shfl_down(s2v, off, 64);
    }
    const int wave = tid >> 6;
    if ((tid & 63) == 0) { w1[wave] = s1v; w2[wave] = s2v; }
    __syncthreads();
    const float sum = w1[0] + w1[1] + w1[2] + w1[3];
    const float ssq = w2[0] + w2[1] + w2[2] + w2[3];
    const float mu = sum * (1.0f / DIM);
    const float var = ssq * (1.0f / DIM) - mu * mu;
    const float rstd = rsqrtf(var + EPS);
    bf16* orow = h + (size_t)t * DIM;
#pragma unroll
    for (int i = 0; i < 4; i++) {
        const int idx = tid + i * 256;
        orow[idx] = (bf16)((v[i] - mu) * rstd * g[idx] + bb[idx]);
    }
}

// ---------------- LayerNorm (standalone, for LN2) ----------------
__global__ __launch_bounds__(256) void ln_kernel(const float* __restrict__ x,
                                                 const float* __restrict__ g,
                                                 const float* __restrict__ b,
                                                 bf16* __restrict__ out) {
    const int t = blockIdx.x;
    const int tid = threadIdx.x;
    const float* row = x + (size_t)t * DIM;
    float v[4];
    float s1 = 0.f, s2 = 0.f;
#pragma unroll
    for (int i = 0; i < 4; i++) {
        v[i] = row[tid + i * 256];
        s1 += v[i];
        s2 += v[i] * v[i];
    }
    __shared__ float w1[4], w2[4];
#pragma unroll
    for (int off = 32; off > 0; off >>= 1) {
        s1 += __shfl_down(s1, off, 64);
        s2 += __shfl_down(s2, off, 64);
    }
    const int wave = tid >> 6;
    if ((tid & 63) == 0) { w1[wave] = s1; w2[wave] = s2; }
    __syncthreads();
    const float sum = w1[0] + w1[1] + w1[2] + w1[3];
    const float ssq = w2[0] + w2[1] + w2[2] + w2[3];
    const float mu = sum * (1.0f / DIM);
    const float var = ssq * (1.0f / DIM) - mu * mu;
    const float rstd = rsqrtf(var + EPS);
    bf16* orow = out + (size_t)t * DIM;
#pragma unroll
    for (int i = 0; i < 4; i++) {
        const int idx = tid + i * 256;
        orow[idx] = (bf16)((v[i] - mu) * rstd * g[idx] + b[idx]);
    }
}

// ---------------- bf16 MFMA GEMM, double-buffered K-pipeline ----------------
// C[M,N] = A[M,K] @ W[N,K]^T + bias (+gelu) (+res). 128x128 tile, BK=32,
// 4 waves each owning a 64x64 quadrant. One barrier per K-iter: prefetch of
// tile k+1 issued right after the barrier overlaps compute on tile k, so the
// next barrier's vmcnt(0) drain waits on loads that aged a full compute phase.
// SPLITK>1: blockIdx.z = K-segment, epilogue atomicAdds fp32 (bias and res
// applied by segment 0 only; Cout must be pre-zeroed or hold the residual).
#define ACT_NONE 0
#define ACT_GELU 1

template <int ACT, bool RES, bool OUT_BF16, bool VT, int SPLITK>
__global__ __launch_bounds__(256) void mfma_gemm(const bf16* __restrict__ A,
                                                 const bf16* __restrict__ W,
                                                 const float* __restrict__ bias,
                                                 const float* __restrict__ res,
                                                 void* __restrict__ Cout,
                                                 bf16* __restrict__ vTout,
                                                 int M, int N, int K) {
    __shared__ __align__(16) bf16 As[2][128 * 32];
    __shared__ __align__(16) bf16 Bs[2][128 * 32];

    const int tid = threadIdx.x;
    const int w = tid >> 6, lane = tid & 63;
    const int bm = blockIdx.y * 128, bn = blockIdx.x * 128;
    const int kseg = K / SPLITK;
    const int k0 = (SPLITK > 1) ? blockIdx.z * kseg : 0;

    const bf16* pa = A + (size_t)(bm + (tid >> 2)) * K + k0 + (tid & 3) * 8;
    const bf16* pb = W + (size_t)(bn + (tid >> 2)) * K + k0 + (tid & 3) * 8;
    const size_t rowskip = (size_t)64 * K;

    const int wm = (w & 1) * 64, wn = (w >> 1) * 64;
    const int fm = lane & 15, fk = (lane >> 4) * 8;
    const int foffA = (wm + fm) * 32 + fk;
    const int foffB = (wn + fm) * 32 + fk;

    f32x4 acc[4][4] = {};

    // prologue: stage tile 0 into buffer 0
    {
        char* lA = (char*)As[0] + (w << 10);
        char* lB = (char*)Bs[0] + (w << 10);
        __builtin_amdgcn_global_load_lds((const AS1 void*)pa, (AS3 void*)lA, 16, 0, 0);
        __builtin_amdgcn_global_load_lds((const AS1 void*)(pa + rowskip), (AS3 void*)(lA + 4096), 16, 0, 0);
        __builtin_amdgcn_global_load_lds((const AS1 void*)pb, (AS3 void*)lB, 16, 0, 0);
        __builtin_amdgcn_global_load_lds((const AS1 void*)(pb + rowskip), (AS3 void*)(lB + 4096), 16, 0, 0);
        pa += 32; pb += 32;
    }

    for (int kk = 0; kk < kseg; kk += 32) {
        const int p = (kk >> 5) & 1;
        __syncthreads();  // completes tile kk's loads; prior readers of buf[1-p] done
        if (kk + 32 < kseg) {
            char* lA = (char*)As[p ^ 1] + (w << 10);
            char* lB = (char*)Bs[p ^ 1] + (w << 10);
            __builtin_amdgcn_global_load_lds((const AS1 void*)pa, (AS3 void*)lA, 16, 0, 0);
            __builtin_amdgcn_global_load_lds((const AS1 void*)(pa + rowskip), (AS3 void*)(lA + 4096), 16, 0, 0);
            __builtin_amdgcn_global_load_lds((const AS1 void*)pb, (AS3 void*)lB, 16, 0, 0);
            __builtin_amdgcn_global_load_lds((const AS1 void*)(pb + rowskip), (AS3 void*)(lB + 4096), 16, 0, 0);
            pa += 32; pb += 32;
        }
        const bf16* ab = As[p] + foffA;
        const bf16* bb = Bs[p] + foffB;
        bf16x8 af[4], bfr[4];
#pragma unroll
        for (int t = 0; t < 4; t++) af[t] = *(const bf16x8*)(ab + t * 16 * 32);
#pragma unroll
        for (int t = 0; t < 4; t++) bfr[t] = *(const bf16x8*)(bb + t * 16 * 32);
#pragma unroll
        for (int mt = 0; mt < 4; mt++)
#pragma unroll
            for (int nt = 0; nt < 4; nt++)
                acc[mt][nt] = __builtin_amdgcn_mfma_f32_16x16x32_bf16(af[mt], bfr[nt], acc[mt][nt], 0, 0, 0);
    }

    // epilogue: D mapping col = lane&15, row = (lane>>4)*4 + reg
    const int cn = bn + wn + fm;
    const int rm = bm + wm + (lane >> 4) * 4;
    float bv[4];
#pragma unroll
    for (int nt = 0; nt < 4; nt++)
        bv[nt] = (SPLITK > 1 && blockIdx.z != 0) ? 0.f : bias[cn + nt * 16];

    if (SPLITK > 1) {
        float* outp = (float*)Cout;
        const bool z0 = (blockIdx.z == 0);
#pragma unroll
        for (int mt = 0; mt < 4; mt++) {
#pragma unroll
            for (int r = 0; r < 4; r++) {
                const size_t rowoff = (size_t)(rm + mt * 16 + r) * N;
#pragma unroll
                for (int nt = 0; nt < 4; nt++) {
                    float val = acc[mt][nt][r] + bv[nt];
                    if (RES && z0) val += res[rowoff + cn + nt * 16];
                    atomicAdd(outp + rowoff + cn + nt * 16, val);
                }
            }
        }
        return;
    }

    if (VT && bn >= 2048) {
        const int dg0 = cn - 2048;
#pragma unroll
        for (int mt = 0; mt < 4; mt++) {
            const int mrow = rm + mt * 16;
            const int bI = mrow >> 10, j0 = mrow & 1023;
#pragma unroll
            for (int nt = 0; nt < 4; nt++) {
                const int dg = dg0 + nt * 16;
                bf16x4 v4 = {(bf16)(acc[mt][nt][0] + bv[nt]), (bf16)(acc[mt][nt][1] + bv[nt]),
                             (bf16)(acc[mt][nt][2] + bv[nt]), (bf16)(acc[mt][nt][3] + bv[nt])};
                *(bf16x4*)(vTout + ((size_t)(bI * 1024 + dg)) * 1024 + j0) = v4;
            }
        }
        return;
    }

#pragma unroll
    for (int mt = 0; mt < 4; mt++) {
#pragma unroll
        for (int r = 0; r < 4; r++) {
            const size_t rowoff = (size_t)(rm + mt * 16 + r) * N;
#pragma unroll
            for (int nt = 0; nt < 4; nt++) {
                float val = acc[mt][nt][r] + bv[nt];
                if (ACT == ACT_GELU) val = 0.5f * val * (1.0f + erff(val * 0.70710678118654752f));
                if (RES) val += res[rowoff + cn + nt * 16];
                if (OUT_BF16) ((bf16*)Cout)[rowoff + cn + nt * 16] = (bf16)val;
                else          ((float*)Cout)[rowoff + cn + nt * 16] = val;
            }
        }
    }
}

// ---------------- MFMA flash attention (unchanged from R4) ----------------
__global__ __launch_bounds__(256) void fattn_mfma(const bf16* __restrict__ qkv,
                                                  const bf16* __restrict__ vT,
                                                  bf16* __restrict__ out) {
    __shared__ __align__(16) bf16 Ks[64 * 64];
    __shared__ __align__(16) bf16 Vt[64 * 64];
    __shared__ __align__(16) bf16 Ps[64 * 68];

    const int bid = blockIdx.x;
    const int qt = bid & 15;
    const int h = (bid >> 4) & 15;
    const int b = bid >> 8;
    const int tid = threadIdx.x;
    const int w = tid >> 6, lane = tid & 63;
    const int li = lane & 15, g = lane >> 4;

    bf16x8 aQ[2];
    {
        const size_t tok = (size_t)b * NSEQ + qt * 64 + w * 16 + li;
#pragma unroll
        for (int ks = 0; ks < 2; ks++)
            aQ[ks] = *(const bf16x8*)(qkv + tok * (3 * DIM) + h * HEAD_DIM + g * 8 + 32 * ks);
    }

    float mrun[4] = {-INFINITY, -INFINITY, -INFINITY, -INFINITY};
    float lrun[4] = {0.f, 0.f, 0.f, 0.f};
    f32x4 o[4] = {};

    const int idx0 = w * 128 + lane;
    const int idx1 = idx0 + 64;
    const int jl0 = idx0 >> 3, c0 = (idx0 & 7) ^ (jl0 & 7);
    const int jl1 = idx1 >> 3, c1 = (idx1 & 7) ^ (jl1 & 7);
    bf16* ldsK0 = Ks + (size_t)(w * 128) * 8;
    bf16* ldsK1 = Ks + (size_t)(w * 128 + 64) * 8;
    bf16* ldsV0 = Vt + (size_t)(w * 128) * 8;
    bf16* ldsV1 = Vt + (size_t)(w * 128 + 64) * 8;
    const bf16* kbase = qkv + (size_t)b * NSEQ * (3 * DIM) + DIM + h * HEAD_DIM;
    const bf16* vbase = vT + ((size_t)b * DIM + h * HEAD_DIM) * NSEQ;

    for (int k0 = 0; k0 < NSEQ; k0 += 64) {
        __syncthreads();
        __builtin_amdgcn_global_load_lds((const AS1 void*)(kbase + (size_t)(k0 + jl0) * (3 * DIM) + c0 * 8),
                                         (AS3 void*)ldsK0, 16, 0, 0);
        __builtin_amdgcn_global_load_lds((const AS1 void*)(kbase + (size_t)(k0 + jl1) * (3 * DIM) + c1 * 8),
                                         (AS3 void*)ldsK1, 16, 0, 0);
        __builtin_amdgcn_global_load_lds((const AS1 void*)(vbase + (size_t)jl0 * NSEQ + k0 + c0 * 8),
                                         (AS3 void*)ldsV0, 16, 0, 0);
        __builtin_amdgcn_global_load_lds((const AS1 void*)(vbase + (size_t)jl1 * NSEQ + k0 + c1 * 8),
                                         (AS3 void*)ldsV1, 16, 0, 0);
        __syncthreads();

        f32x4 s[4] = {};
#pragma unroll
        for (int ks = 0; ks < 2; ks++) {
#pragma unroll
            for (int nt = 0; nt < 4; nt++) {
                const int j = li + 16 * nt;
                const int p = (g + 4 * ks) ^ (j & 7);
                bf16x8 bK = *(const bf16x8*)(Ks + j * 64 + p * 8);
                s[nt] = __builtin_amdgcn_mfma_f32_16x16x32_bf16(aQ[ks], bK, s[nt], 0, 0, 0);
            }
        }
#pragma unroll
        for (int nt = 0; nt < 4; nt++) s[nt] *= 0.125f;

        float m4[4], rs[4], alpha[4];
#pragma unroll
        for (int r = 0; r < 4; r++)
            m4[r] = fmaxf(fmaxf(s[0][r], s[1][r]), fmaxf(s[2][r], s[3][r]));
#pragma unroll
        for (int mask = 1; mask < 16; mask <<= 1)
#pragma unroll
            for (int r = 0; r < 4; r++) m4[r] = fmaxf(m4[r], __shfl_xor(m4[r], mask, 64));
#pragma unroll
        for (int r = 0; r < 4; r++) {
            const float mn = fmaxf(mrun[r], m4[r]);
            alpha[r] = __expf(mrun[r] - mn);
            mrun[r] = mn;
        }
#pragma unroll
        for (int r = 0; r < 4; r++) rs[r] = 0.f;
#pragma unroll
        for (int nt = 0; nt < 4; nt++) {
#pragma unroll
            for (int r = 0; r < 4; r++) {
                const float p = __expf(s[nt][r] - mrun[r]);
                rs[r] += p;
                Ps[(w * 16 + g * 4 + r) * 68 + li + 16 * nt] = (bf16)p;
            }
        }
#pragma unroll
        for (int mask = 1; mask < 16; mask <<= 1)
#pragma unroll
            for (int r = 0; r < 4; r++) rs[r] += __shfl_xor(rs[r], mask, 64);
#pragma unroll
        for (int r = 0; r < 4; r++) lrun[r] = lrun[r] * alpha[r] + rs[r];
#pragma unroll
        for (int nt = 0; nt < 4; nt++)
#pragma unroll
            for (int r = 0; r < 4; r++) o[nt][r] *= alpha[r];

        bf16x8 aP[2];
#pragma unroll
        for (int ks = 0; ks < 2; ks++) {
            const int off = (w * 16 + li) * 68 + g * 8 + 32 * ks;
            bf16x4 lo = *(const bf16x4*)(Ps + off);
            bf16x4 hi = *(const bf16x4*)(Ps + off + 4);
            aP[ks] = bf16x8{lo[0], lo[1], lo[2], lo[3], hi[0], hi[1], hi[2], hi[3]};
        }
#pragma unroll
        for (int ks = 0; ks < 2; ks++) {
#pragma unroll
            for (int nt = 0; nt < 4; nt++) {
                const int d = li + 16 * nt;
                const int p = (g + 4 * ks) ^ (d & 7);
                bf16x8 bV = *(const bf16x8*)(Vt + d * 64 + p * 8);
                o[nt] = __builtin_amdgcn_mfma_f32_16x16x32_bf16(aP[ks], bV, o[nt], 0, 0, 0);
            }
        }
    }

    float linv[4];
#pragma unroll
    for (int r = 0; r < 4; r++) linv[r] = 1.0f / lrun[r];
    const size_t tok0 = (size_t)b * NSEQ + qt * 64 + w * 16 + g * 4;
#pragma unroll
    for (int r = 0; r < 4; r++) {
#pragma unroll
        for (int nt = 0; nt < 4; nt++)
            out[(tok0 + r) * DIM + h * HEAD_DIM + 16 * nt + li] = (bf16)(o[nt][r] * linv[r]);
    }
}

// ---------------- launch ----------------
extern "C" void kernel_launch(void* const* d_in, const int* in_sizes, int n_in,
                              void* d_out, int out_size, void* d_ws, size_t ws_size,
                              hipStream_t stream) {
    const float* x      = (const float*)d_in[0];
    const float* ln1_g  = (const float*)d_in[1];
    const float* ln1_b  = (const float*)d_in[2];
    const float* qkv_w  = (const float*)d_in[3];
    const float* qkv_b  = (const float*)d_in[4];
    const float* proj_w = (const float*)d_in[5];
    const float* proj_b = (const float*)d_in[6];
    const float* ln2_g  = (const float*)d_in[7];
    const float* ln2_b  = (const float*)d_in[8];
    const float* fc1_w  = (const float*)d_in[9];
    const float* fc1_b  = (const float*)d_in[10];
    const float* fc2_w  = (const float*)d_in[11];
    const float* fc2_b  = (const float*)d_in[12];
    float* out = (float*)d_out;

    char* p = (char*)d_ws;
    bf16*  h_bf    = (bf16*)p;  p += (size_t)TOKENS * DIM * 2;
    bf16*  attn_bf = (bf16*)p;  p += (size_t)TOKENS * DIM * 2;
    bf16*  ffn_bf  = (bf16*)p;  p += (size_t)TOKENS * HIDDEN * 2;
    bf16*  qkv_bf  = (bf16*)p;  p += (size_t)TOKENS * 3 * DIM * 2;
    bf16*  vT_bf   = (bf16*)p;  p += (size_t)BATCH * DIM * NSEQ * 2;
    bf16*  wq_bf   = (bf16*)p;  p += (size_t)3 * DIM * DIM * 2;
    bf16*  wp_bf   = (bf16*)p;  p += (size_t)DIM * DIM * 2;
    bf16*  w1_bf   = (bf16*)p;  p += (size_t)HIDDEN * DIM * 2;
    bf16*  w2_bf   = (bf16*)p;  p += (size_t)DIM * HIDDEN * 2;

    // 0) fused weight convert + LN1
    prep_kernel<<<CVT_BLOCKS + TOKENS, 256, 0, stream>>>(
        x, ln1_g, ln1_b, h_bf, qkv_w, proj_w, fc1_w, fc2_w, wq_bf, wp_bf, w1_bf, w2_bf);
    // 1) qkv = h @ qkv_w^T + b -> bf16 (Q,K) + transposed V -> vT_bf
    mfma_gemm<ACT_NONE, false, true, true, 1><<<dim3(3 * DIM / 128, TOKENS / 128), 256, 0, stream>>>(
        h_bf, wq_bf, qkv_b, nullptr, qkv_bf, vT_bf, TOKENS, 3 * DIM, DIM);
    // 2) MFMA flash attention -> bf16
    fattn_mfma<<<BATCH * HEADS * (NSEQ / 64), 256, 0, stream>>>(qkv_bf, vT_bf, attn_bf);
    // 3) out = 0; out += attn @ proj_w^T + b + x  (split-K 4, atomic; res via z=0)
    hipMemsetAsync(out, 0, (size_t)TOKENS * DIM * sizeof(float), stream);
    mfma_gemm<ACT_NONE, true, false, false, 4><<<dim3(DIM / 128, TOKENS / 128, 4), 256, 0, stream>>>(
        attn_bf, wp_bf, proj_b, x, out, nullptr, TOKENS, DIM, DIM);
    // 4) h2 = LN2(x1) -> bf16
    ln_kernel<<<TOKENS, 256, 0, stream>>>(out, ln2_g, ln2_b, h_bf);
    // 5) ffn = gelu(h2 @ fc1_w^T + b) -> bf16
    mfma_gemm<ACT_GELU, false, true, false, 1><<<dim3(HIDDEN / 128, TOKENS / 128), 256, 0, stream>>>(
        h_bf, w1_bf, fc1_b, nullptr, ffn_bf, nullptr, TOKENS, HIDDEN, DIM);
    // 6) out += ffn @ fc2_w^T + b  (split-K 4, atomic; out already holds x1)
    mfma_gemm<ACT_NONE, false, false, false, 4><<<dim3(DIM / 128, TOKENS / 128, 4), 256, 0, stream>>>(
        ffn_bf, w2_bf, fc2_b, nullptr, out, nullptr, TOKENS, DIM, HIDDEN);
}

// Round 7
// 399.686 us; speedup vs baseline: 1.1258x; 1.1258x over previous
//
#include <hip/hip_runtime.h>
#include <math.h>

#define DIM 1024
#define HEADS 16
#define HEAD_DIM 64
#define HIDDEN 4096
#define NSEQ 1024
#define BATCH 4
#define TOKENS (BATCH * NSEQ)
#define EPS 1e-5f

typedef __bf16 bf16;
typedef __bf16 bf16x4 __attribute__((ext_vector_type(4)));
typedef __bf16 bf16x8 __attribute__((ext_vector_type(8)));
typedef float f32x4 __attribute__((ext_vector_type(4)));

#define AS1 __attribute__((address_space(1)))
#define AS3 __attribute__((address_space(3)))

#define CVT_QUADS 3145728   // (3M+1M+4M+4M)/4 total weight quads
#define CVT_BLOCKS 12288    // CVT_QUADS/256

// ---------------- prep: fused weight-convert + LN1 ----------------
__global__ __launch_bounds__(256) void prep_kernel(const float* __restrict__ x,
                                                   const float* __restrict__ g,
                                                   const float* __restrict__ bb,
                                                   bf16* __restrict__ h,
                                                   const float* __restrict__ s0,
                                                   const float* __restrict__ s1,
                                                   const float* __restrict__ s2,
                                                   const float* __restrict__ s3,
                                                   bf16* __restrict__ d0,
                                                   bf16* __restrict__ d1,
                                                   bf16* __restrict__ d2,
                                                   bf16* __restrict__ d3) {
    const int blk = blockIdx.x;
    const int tid = threadIdx.x;
    if (blk < CVT_BLOCKS) {
        size_t q = (size_t)blk * 256 + tid;
        const float* s;
        bf16* d;
        if (q < 786432) { s = s0; d = d0; }
        else if (q < 786432 + 262144) { q -= 786432; s = s1; d = d1; }
        else if (q < 786432 + 262144 + 1048576) { q -= 786432 + 262144; s = s2; d = d2; }
        else { q -= 786432 + 262144 + 1048576; s = s3; d = d3; }
        const float4 v = *(const float4*)(s + q * 4);
        bf16x4 o = {(bf16)v.x, (bf16)v.y, (bf16)v.z, (bf16)v.w};
        *(bf16x4*)(d + q * 4) = o;
        return;
    }
    const int t = blk - CVT_BLOCKS;
    const float* row = x + (size_t)t * DIM;
    float v[4];
    float s1v = 0.f, s2v = 0.f;
#pragma unroll
    for (int i = 0; i < 4; i++) {
        v[i] = row[tid + i * 256];
        s1v += v[i];
        s2v += v[i] * v[i];
    }
    __shared__ float w1[4], w2[4];
#pragma unroll
    for (int off = 32; off > 0; off >>= 1) {
        s1v += __shfl_down(s1v, off, 64);
        s2v += __shfl_down(s2v, off, 64);
    }
    const int wave = tid >> 6;
    if ((tid & 63) == 0) { w1[wave] = s1v; w2[wave] = s2v; }
    __syncthreads();
    const float sum = w1[0] + w1[1] + w1[2] + w1[3];
    const float ssq = w2[0] + w2[1] + w2[2] + w2[3];
    const float mu = sum * (1.0f / DIM);
    const float var = ssq * (1.0f / DIM) - mu * mu;
    const float rstd = rsqrtf(var + EPS);
    bf16* orow = h + (size_t)t * DIM;
#pragma unroll
    for (int i = 0; i < 4; i++) {
        const int idx = tid + i * 256;
        orow[idx] = (bf16)((v[i] - mu) * rstd * g[idx] + bb[idx]);
    }
}

// ---------------- fused residual-add + LN2 ----------------
// x1 = x + p0 + p1 + proj_b; out_f32 = x1; h2 = LN(x1) (bf16)
__global__ __launch_bounds__(256) void ln2add_kernel(const float* __restrict__ x,
                                                     const bf16* __restrict__ p0,
                                                     const bf16* __restrict__ p1,
                                                     const float* __restrict__ pb,
                                                     const float* __restrict__ g,
                                                     const float* __restrict__ b,
                                                     float* __restrict__ out,
                                                     bf16* __restrict__ h2) {
    const int t = blockIdx.x;
    const int tid = threadIdx.x;
    const size_t base = (size_t)t * DIM;
    float v[4];
    float s1 = 0.f, s2 = 0.f;
#pragma unroll
    for (int i = 0; i < 4; i++) {
        const int idx = tid + i * 256;
        const float val = x[base + idx] + (float)p0[base + idx] + (float)p1[base + idx] + pb[idx];
        v[i] = val;
        out[base + idx] = val;
        s1 += val;
        s2 += val * val;
    }
    __shared__ float w1[4], w2[4];
#pragma unroll
    for (int off = 32; off > 0; off >>= 1) {
        s1 += __shfl_down(s1, off, 64);
        s2 += __shfl_down(s2, off, 64);
    }
    const int wave = tid >> 6;
    if ((tid & 63) == 0) { w1[wave] = s1; w2[wave] = s2; }
    __syncthreads();
    const float sum = w1[0] + w1[1] + w1[2] + w1[3];
    const float ssq = w2[0] + w2[1] + w2[2] + w2[3];
    const float mu = sum * (1.0f / DIM);
    const float var = ssq * (1.0f / DIM) - mu * mu;
    const float rstd = rsqrtf(var + EPS);
    bf16* orow = h2 + base;
#pragma unroll
    for (int i = 0; i < 4; i++) {
        const int idx = tid + i * 256;
        orow[idx] = (bf16)((v[i] - mu) * rstd * g[idx] + b[idx]);
    }
}

// ---------------- final reducer: out += q0+q1+q2+q3 + fc2_b ----------------
__global__ __launch_bounds__(256) void add2_kernel(float* __restrict__ out,
                                                   const bf16* __restrict__ q0,
                                                   const bf16* __restrict__ q1,
                                                   const bf16* __restrict__ q2,
                                                   const bf16* __restrict__ q3,
                                                   const float* __restrict__ bias) {
    const size_t i = ((size_t)blockIdx.x * 256 + threadIdx.x) * 4;
    const int col = (int)(i & (DIM - 1));
    float4 o = *(const float4*)(out + i);
    const float4 bv = *(const float4*)(bias + col);
    bf16x4 a0 = *(const bf16x4*)(q0 + i);
    bf16x4 a1 = *(const bf16x4*)(q1 + i);
    bf16x4 a2 = *(const bf16x4*)(q2 + i);
    bf16x4 a3 = *(const bf16x4*)(q3 + i);
    o.x += (float)a0[0] + (float)a1[0] + (float)a2[0] + (float)a3[0] + bv.x;
    o.y += (float)a0[1] + (float)a1[1] + (float)a2[1] + (float)a3[1] + bv.y;
    o.z += (float)a0[2] + (float)a1[2] + (float)a2[2] + (float)a3[2] + bv.z;
    o.w += (float)a0[3] + (float)a1[3] + (float)a2[3] + (float)a3[3] + bv.w;
    *(float4*)(out + i) = o;
}

// ---------------- bf16 MFMA GEMM (m97 single-buffer structure, R5-proven) ----------------
// C[M,N] = A[M,K] @ W[N,K]^T. 128x128 tile, BK=32, 4 waves = 64x64 quadrants.
// SPLITK==1: epilogue adds bias (+gelu), writes bf16 or fp32; VT handles the
//   V third of QKV transposed.
// SPLITK>1: blockIdx.z = K-segment; raw fp32 acc rounded to bf16 and STORED
//   (no atomics) to part + z*M*N; bias applied later by the reducer.
#define ACT_NONE 0
#define ACT_GELU 1

template <int ACT, bool OUT_BF16, bool VT, int SPLITK>
__global__ __launch_bounds__(256) void mfma_gemm(const bf16* __restrict__ A,
                                                 const bf16* __restrict__ W,
                                                 const float* __restrict__ bias,
                                                 void* __restrict__ Cout,
                                                 bf16* __restrict__ vTout,
                                                 bf16* __restrict__ part,
                                                 int M, int N, int K) {
    __shared__ __align__(16) bf16 As[128 * 32];
    __shared__ __align__(16) bf16 Bs[128 * 32];

    const int tid = threadIdx.x;
    const int w = tid >> 6, lane = tid & 63;
    const int bm = blockIdx.y * 128, bn = blockIdx.x * 128;
    const int kseg = K / SPLITK;
    const int k0 = (SPLITK > 1) ? blockIdx.z * kseg : 0;

    const bf16* pa = A + (size_t)(bm + (tid >> 2)) * K + k0 + (tid & 3) * 8;
    const bf16* pb = W + (size_t)(bn + (tid >> 2)) * K + k0 + (tid & 3) * 8;
    const size_t rowskip = (size_t)64 * K;
    char* ldsA = (char*)As + (w << 10);
    char* ldsB = (char*)Bs + (w << 10);

    const int wm = (w & 1) * 64, wn = (w >> 1) * 64;
    const int fm = lane & 15, fk = (lane >> 4) * 8;
    const bf16* aoff = As + (wm + fm) * 32 + fk;
    const bf16* boff = Bs + (wn + fm) * 32 + fk;

    f32x4 acc[4][4] = {};

    for (int kk = 0; kk < kseg; kk += 32) {
        __builtin_amdgcn_global_load_lds((const AS1 void*)pa, (AS3 void*)ldsA, 16, 0, 0);
        __builtin_amdgcn_global_load_lds((const AS1 void*)(pa + rowskip), (AS3 void*)(ldsA + 4096), 16, 0, 0);
        __builtin_amdgcn_global_load_lds((const AS1 void*)pb, (AS3 void*)ldsB, 16, 0, 0);
        __builtin_amdgcn_global_load_lds((const AS1 void*)(pb + rowskip), (AS3 void*)(ldsB + 4096), 16, 0, 0);
        pa += 32; pb += 32;
        __syncthreads();

        bf16x8 af[4], bfr[4];
#pragma unroll
        for (int t = 0; t < 4; t++) af[t] = *(const bf16x8*)(aoff + t * 16 * 32);
#pragma unroll
        for (int t = 0; t < 4; t++) bfr[t] = *(const bf16x8*)(boff + t * 16 * 32);
#pragma unroll
        for (int mt = 0; mt < 4; mt++)
#pragma unroll
            for (int nt = 0; nt < 4; nt++)
                acc[mt][nt] = __builtin_amdgcn_mfma_f32_16x16x32_bf16(af[mt], bfr[nt], acc[mt][nt], 0, 0, 0);
        __syncthreads();
    }

    // epilogue: D mapping col = lane&15, row = (lane>>4)*4 + reg
    const int cn = bn + wn + fm;
    const int rm = bm + wm + (lane >> 4) * 4;

    if (SPLITK > 1) {
        bf16* pp = part + (size_t)blockIdx.z * M * N;
#pragma unroll
        for (int mt = 0; mt < 4; mt++) {
#pragma unroll
            for (int r = 0; r < 4; r++) {
                const size_t rowoff = (size_t)(rm + mt * 16 + r) * N;
#pragma unroll
                for (int nt = 0; nt < 4; nt++)
                    pp[rowoff + cn + nt * 16] = (bf16)acc[mt][nt][r];
            }
        }
        return;
    }

    float bv[4];
#pragma unroll
    for (int nt = 0; nt < 4; nt++) bv[nt] = bias[cn + nt * 16];

    if (VT && bn >= 2048) {
        const int dg0 = cn - 2048;
#pragma unroll
        for (int mt = 0; mt < 4; mt++) {
            const int mrow = rm + mt * 16;
            const int bI = mrow >> 10, j0 = mrow & 1023;
#pragma unroll
            for (int nt = 0; nt < 4; nt++) {
                const int dg = dg0 + nt * 16;
                bf16x4 v4 = {(bf16)(acc[mt][nt][0] + bv[nt]), (bf16)(acc[mt][nt][1] + bv[nt]),
                             (bf16)(acc[mt][nt][2] + bv[nt]), (bf16)(acc[mt][nt][3] + bv[nt])};
                *(bf16x4*)(vTout + ((size_t)(bI * 1024 + dg)) * 1024 + j0) = v4;
            }
        }
        return;
    }

#pragma unroll
    for (int mt = 0; mt < 4; mt++) {
#pragma unroll
        for (int r = 0; r < 4; r++) {
            const size_t rowoff = (size_t)(rm + mt * 16 + r) * N;
#pragma unroll
            for (int nt = 0; nt < 4; nt++) {
                float val = acc[mt][nt][r] + bv[nt];
                if (ACT == ACT_GELU) val = 0.5f * val * (1.0f + erff(val * 0.70710678118654752f));
                if (OUT_BF16) ((bf16*)Cout)[rowoff + cn + nt * 16] = (bf16)val;
                else          ((float*)Cout)[rowoff + cn + nt * 16] = val;
            }
        }
    }
}

// ---------------- MFMA flash attention (R4-proven) ----------------
__global__ __launch_bounds__(256) void fattn_mfma(const bf16* __restrict__ qkv,
                                                  const bf16* __restrict__ vT,
                                                  bf16* __restrict__ out) {
    __shared__ __align__(16) bf16 Ks[64 * 64];
    __shared__ __align__(16) bf16 Vt[64 * 64];
    __shared__ __align__(16) bf16 Ps[64 * 68];

    const int bid = blockIdx.x;
    const int qt = bid & 15;
    const int h = (bid >> 4) & 15;
    const int b = bid >> 8;
    const int tid = threadIdx.x;
    const int w = tid >> 6, lane = tid & 63;
    const int li = lane & 15, g = lane >> 4;

    bf16x8 aQ[2];
    {
        const size_t tok = (size_t)b * NSEQ + qt * 64 + w * 16 + li;
#pragma unroll
        for (int ks = 0; ks < 2; ks++)
            aQ[ks] = *(const bf16x8*)(qkv + tok * (3 * DIM) + h * HEAD_DIM + g * 8 + 32 * ks);
    }

    float mrun[4] = {-INFINITY, -INFINITY, -INFINITY, -INFINITY};
    float lrun[4] = {0.f, 0.f, 0.f, 0.f};
    f32x4 o[4] = {};

    const int idx0 = w * 128 + lane;
    const int idx1 = idx0 + 64;
    const int jl0 = idx0 >> 3, c0 = (idx0 & 7) ^ (jl0 & 7);
    const int jl1 = idx1 >> 3, c1 = (idx1 & 7) ^ (jl1 & 7);
    bf16* ldsK0 = Ks + (size_t)(w * 128) * 8;
    bf16* ldsK1 = Ks + (size_t)(w * 128 + 64) * 8;
    bf16* ldsV0 = Vt + (size_t)(w * 128) * 8;
    bf16* ldsV1 = Vt + (size_t)(w * 128 + 64) * 8;
    const bf16* kbase = qkv + (size_t)b * NSEQ * (3 * DIM) + DIM + h * HEAD_DIM;
    const bf16* vbase = vT + ((size_t)b * DIM + h * HEAD_DIM) * NSEQ;

    for (int k0 = 0; k0 < NSEQ; k0 += 64) {
        __syncthreads();
        __builtin_amdgcn_global_load_lds((const AS1 void*)(kbase + (size_t)(k0 + jl0) * (3 * DIM) + c0 * 8),
                                         (AS3 void*)ldsK0, 16, 0, 0);
        __builtin_amdgcn_global_load_lds((const AS1 void*)(kbase + (size_t)(k0 + jl1) * (3 * DIM) + c1 * 8),
                                         (AS3 void*)ldsK1, 16, 0, 0);
        __builtin_amdgcn_global_load_lds((const AS1 void*)(vbase + (size_t)jl0 * NSEQ + k0 + c0 * 8),
                                         (AS3 void*)ldsV0, 16, 0, 0);
        __builtin_amdgcn_global_load_lds((const AS1 void*)(vbase + (size_t)jl1 * NSEQ + k0 + c1 * 8),
                                         (AS3 void*)ldsV1, 16, 0, 0);
        __syncthreads();

        f32x4 s[4] = {};
#pragma unroll
        for (int ks = 0; ks < 2; ks++) {
#pragma unroll
            for (int nt = 0; nt < 4; nt++) {
                const int j = li + 16 * nt;
                const int p = (g + 4 * ks) ^ (j & 7);
                bf16x8 bK = *(const bf16x8*)(Ks + j * 64 + p * 8);
                s[nt] = __builtin_amdgcn_mfma_f32_16x16x32_bf16(aQ[ks], bK, s[nt], 0, 0, 0);
            }
        }
#pragma unroll
        for (int nt = 0; nt < 4; nt++) s[nt] *= 0.125f;

        float m4[4], rs[4], alpha[4];
#pragma unroll
        for (int r = 0; r < 4; r++)
            m4[r] = fmaxf(fmaxf(s[0][r], s[1][r]), fmaxf(s[2][r], s[3][r]));
#pragma unroll
        for (int mask = 1; mask < 16; mask <<= 1)
#pragma unroll
            for (int r = 0; r < 4; r++) m4[r] = fmaxf(m4[r], __shfl_xor(m4[r], mask, 64));
#pragma unroll
        for (int r = 0; r < 4; r++) {
            const float mn = fmaxf(mrun[r], m4[r]);
            alpha[r] = __expf(mrun[r] - mn);
            mrun[r] = mn;
        }
#pragma unroll
        for (int r = 0; r < 4; r++) rs[r] = 0.f;
#pragma unroll
        for (int nt = 0; nt < 4; nt++) {
#pragma unroll
            for (int r = 0; r < 4; r++) {
                const float p = __expf(s[nt][r] - mrun[r]);
                rs[r] += p;
                Ps[(w * 16 + g * 4 + r) * 68 + li + 16 * nt] = (bf16)p;
            }
        }
#pragma unroll
        for (int mask = 1; mask < 16; mask <<= 1)
#pragma unroll
            for (int r = 0; r < 4; r++) rs[r] += __shfl_xor(rs[r], mask, 64);
#pragma unroll
        for (int r = 0; r < 4; r++) lrun[r] = lrun[r] * alpha[r] + rs[r];
#pragma unroll
        for (int nt = 0; nt < 4; nt++)
#pragma unroll
            for (int r = 0; r < 4; r++) o[nt][r] *= alpha[r];

        bf16x8 aP[2];
#pragma unroll
        for (int ks = 0; ks < 2; ks++) {
            const int off = (w * 16 + li) * 68 + g * 8 + 32 * ks;
            bf16x4 lo = *(const bf16x4*)(Ps + off);
            bf16x4 hi = *(const bf16x4*)(Ps + off + 4);
            aP[ks] = bf16x8{lo[0], lo[1], lo[2], lo[3], hi[0], hi[1], hi[2], hi[3]};
        }
#pragma unroll
        for (int ks = 0; ks < 2; ks++) {
#pragma unroll
            for (int nt = 0; nt < 4; nt++) {
                const int d = li + 16 * nt;
                const int p = (g + 4 * ks) ^ (d & 7);
                bf16x8 bV = *(const bf16x8*)(Vt + d * 64 + p * 8);
                o[nt] = __builtin_amdgcn_mfma_f32_16x16x32_bf16(aP[ks], bV, o[nt], 0, 0, 0);
            }
        }
    }

    float linv[4];
#pragma unroll
    for (int r = 0; r < 4; r++) linv[r] = 1.0f / lrun[r];
    const size_t tok0 = (size_t)b * NSEQ + qt * 64 + w * 16 + g * 4;
#pragma unroll
    for (int r = 0; r < 4; r++) {
#pragma unroll
        for (int nt = 0; nt < 4; nt++)
            out[(tok0 + r) * DIM + h * HEAD_DIM + 16 * nt + li] = (bf16)(o[nt][r] * linv[r]);
    }
}

// ---------------- launch ----------------
extern "C" void kernel_launch(void* const* d_in, const int* in_sizes, int n_in,
                              void* d_out, int out_size, void* d_ws, size_t ws_size,
                              hipStream_t stream) {
    const float* x      = (const float*)d_in[0];
    const float* ln1_g  = (const float*)d_in[1];
    const float* ln1_b  = (const float*)d_in[2];
    const float* qkv_w  = (const float*)d_in[3];
    const float* qkv_b  = (const float*)d_in[4];
    const float* proj_w = (const float*)d_in[5];
    const float* proj_b = (const float*)d_in[6];
    const float* ln2_g  = (const float*)d_in[7];
    const float* ln2_b  = (const float*)d_in[8];
    const float* fc1_w  = (const float*)d_in[9];
    const float* fc1_b  = (const float*)d_in[10];
    const float* fc2_w  = (const float*)d_in[11];
    const float* fc2_b  = (const float*)d_in[12];
    float* out = (float*)d_out;

    char* p = (char*)d_ws;
    bf16*  h_bf    = (bf16*)p;  p += (size_t)TOKENS * DIM * 2;         // 8MB
    bf16*  attn_bf = (bf16*)p;  p += (size_t)TOKENS * DIM * 2;         // 8MB
    bf16*  ffn_bf  = (bf16*)p;  p += (size_t)TOKENS * HIDDEN * 2;      // 32MB
    bf16*  qkv_bf  = (bf16*)p;  p += (size_t)TOKENS * 3 * DIM * 2;     // 24MB (dead after fattn)
    bf16*  vT_bf   = (bf16*)p;  p += (size_t)BATCH * DIM * NSEQ * 2;   // 8MB  (dead after fattn)
    bf16*  wq_bf   = (bf16*)p;  p += (size_t)3 * DIM * DIM * 2;
    bf16*  wp_bf   = (bf16*)p;  p += (size_t)DIM * DIM * 2;
    bf16*  w1_bf   = (bf16*)p;  p += (size_t)HIDDEN * DIM * 2;
    bf16*  w2_bf   = (bf16*)p;  p += (size_t)DIM * HIDDEN * 2;
    // partial buffers overlay the dead qkv/vT region (32MB):
    bf16*  proj_part = qkv_bf;   // 2 x 8MB  (proj split-K, used before fc2)
    bf16*  fc2_part  = qkv_bf;   // 4 x 8MB  (fc2 split-K, after proj_part dead)

    // 0) fused weight convert + LN1
    prep_kernel<<<CVT_BLOCKS + TOKENS, 256, 0, stream>>>(
        x, ln1_g, ln1_b, h_bf, qkv_w, proj_w, fc1_w, fc2_w, wq_bf, wp_bf, w1_bf, w2_bf);
    // 1) qkv = h @ qkv_w^T + b -> bf16 (Q,K) + transposed V -> vT_bf
    mfma_gemm<ACT_NONE, true, true, 1><<<dim3(3 * DIM / 128, TOKENS / 128), 256, 0, stream>>>(
        h_bf, wq_bf, qkv_b, qkv_bf, vT_bf, nullptr, TOKENS, 3 * DIM, DIM);
    // 2) MFMA flash attention -> bf16
    fattn_mfma<<<BATCH * HEADS * (NSEQ / 64), 256, 0, stream>>>(qkv_bf, vT_bf, attn_bf);
    // 3) proj partials (split-K 2, bf16 stores, no bias)
    mfma_gemm<ACT_NONE, false, false, 2><<<dim3(DIM / 128, TOKENS / 128, 2), 256, 0, stream>>>(
        attn_bf, wp_bf, proj_b, nullptr, nullptr, proj_part, TOKENS, DIM, DIM);
    // 4) x1 = x + p0 + p1 + proj_b -> out; h2 = LN2(x1) -> bf16
    ln2add_kernel<<<TOKENS, 256, 0, stream>>>(
        x, proj_part, proj_part + (size_t)TOKENS * DIM, proj_b, ln2_g, ln2_b, out, h_bf);
    // 5) ffn = gelu(h2 @ fc1_w^T + b) -> bf16
    mfma_gemm<ACT_GELU, true, false, 1><<<dim3(HIDDEN / 128, TOKENS / 128), 256, 0, stream>>>(
        h_bf, w1_bf, fc1_b, ffn_bf, nullptr, nullptr, TOKENS, HIDDEN, DIM);
    // 6) fc2 partials (split-K 4, bf16 stores)
    mfma_gemm<ACT_NONE, false, false, 4><<<dim3(DIM / 128, TOKENS / 128, 4), 256, 0, stream>>>(
        ffn_bf, w2_bf, fc2_b, nullptr, nullptr, fc2_part, TOKENS, DIM, HIDDEN);
    // 7) out = x1 + q0+q1+q2+q3 + fc2_b
    add2_kernel<<<TOKENS * DIM / 1024, 256, 0, stream>>>(
        out, fc2_part, fc2_part + (size_t)TOKENS * DIM, fc2_part + (size_t)2 * TOKENS * DIM,
        fc2_part + (size_t)3 * TOKENS * DIM, fc2_b);
}

// Round 8
// 364.965 us; speedup vs baseline: 1.2329x; 1.0951x over previous
//
#include <hip/hip_runtime.h>
#include <math.h>

#define DIM 1024
#define HEADS 16
#define HEAD_DIM 64
#define HIDDEN 4096
#define NSEQ 1024
#define BATCH 4
#define TOKENS (BATCH * NSEQ)
#define EPS 1e-5f

typedef __bf16 bf16;
typedef __bf16 bf16x4 __attribute__((ext_vector_type(4)));
typedef __bf16 bf16x8 __attribute__((ext_vector_type(8)));
typedef float f32x4 __attribute__((ext_vector_type(4)));

#define AS1 __attribute__((address_space(1)))
#define AS3 __attribute__((address_space(3)))

#define CVT_QUADS 3145728   // (3M+1M+4M+4M)/4 total weight quads
#define CVT_BLOCKS 12288    // CVT_QUADS/256

// ---------------- prep: fused weight-convert + LN1 ----------------
__global__ __launch_bounds__(256) void prep_kernel(const float* __restrict__ x,
                                                   const float* __restrict__ g,
                                                   const float* __restrict__ bb,
                                                   bf16* __restrict__ h,
                                                   const float* __restrict__ s0,
                                                   const float* __restrict__ s1,
                                                   const float* __restrict__ s2,
                                                   const float* __restrict__ s3,
                                                   bf16* __restrict__ d0,
                                                   bf16* __restrict__ d1,
                                                   bf16* __restrict__ d2,
                                                   bf16* __restrict__ d3) {
    const int blk = blockIdx.x;
    const int tid = threadIdx.x;
    if (blk < CVT_BLOCKS) {
        size_t q = (size_t)blk * 256 + tid;
        const float* s;
        bf16* d;
        if (q < 786432) { s = s0; d = d0; }
        else if (q < 786432 + 262144) { q -= 786432; s = s1; d = d1; }
        else if (q < 786432 + 262144 + 1048576) { q -= 786432 + 262144; s = s2; d = d2; }
        else { q -= 786432 + 262144 + 1048576; s = s3; d = d3; }
        const float4 v = *(const float4*)(s + q * 4);
        bf16x4 o = {(bf16)v.x, (bf16)v.y, (bf16)v.z, (bf16)v.w};
        *(bf16x4*)(d + q * 4) = o;
        return;
    }
    const int t = blk - CVT_BLOCKS;
    const float* row = x + (size_t)t * DIM;
    float v[4];
    float s1v = 0.f, s2v = 0.f;
#pragma unroll
    for (int i = 0; i < 4; i++) {
        v[i] = row[tid + i * 256];
        s1v += v[i];
        s2v += v[i] * v[i];
    }
    __shared__ float w1[4], w2[4];
#pragma unroll
    for (int off = 32; off > 0; off >>= 1) {
        s1v += __shfl_down(s1v, off, 64);
        s2v += __shfl_down(s2v, off, 64);
    }
    const int wave = tid >> 6;
    if ((tid & 63) == 0) { w1[wave] = s1v; w2[wave] = s2v; }
    __syncthreads();
    const float sum = w1[0] + w1[1] + w1[2] + w1[3];
    const float ssq = w2[0] + w2[1] + w2[2] + w2[3];
    const float mu = sum * (1.0f / DIM);
    const float var = ssq * (1.0f / DIM) - mu * mu;
    const float rstd = rsqrtf(var + EPS);
    bf16* orow = h + (size_t)t * DIM;
#pragma unroll
    for (int i = 0; i < 4; i++) {
        const int idx = tid + i * 256;
        orow[idx] = (bf16)((v[i] - mu) * rstd * g[idx] + bb[idx]);
    }
}

// ---------------- fused residual-add + LN2 ----------------
__global__ __launch_bounds__(256) void ln2add_kernel(const float* __restrict__ x,
                                                     const bf16* __restrict__ p0,
                                                     const bf16* __restrict__ p1,
                                                     const float* __restrict__ pb,
                                                     const float* __restrict__ g,
                                                     const float* __restrict__ b,
                                                     float* __restrict__ out,
                                                     bf16* __restrict__ h2) {
    const int t = blockIdx.x;
    const int tid = threadIdx.x;
    const size_t base = (size_t)t * DIM;
    float v[4];
    float s1 = 0.f, s2 = 0.f;
#pragma unroll
    for (int i = 0; i < 4; i++) {
        const int idx = tid + i * 256;
        const float val = x[base + idx] + (float)p0[base + idx] + (float)p1[base + idx] + pb[idx];
        v[i] = val;
        out[base + idx] = val;
        s1 += val;
        s2 += val * val;
    }
    __shared__ float w1[4], w2[4];
#pragma unroll
    for (int off = 32; off > 0; off >>= 1) {
        s1 += __shfl_down(s1, off, 64);
        s2 += __shfl_down(s2, off, 64);
    }
    const int wave = tid >> 6;
    if ((tid & 63) == 0) { w1[wave] = s1; w2[wave] = s2; }
    __syncthreads();
    const float sum = w1[0] + w1[1] + w1[2] + w1[3];
    const float ssq = w2[0] + w2[1] + w2[2] + w2[3];
    const float mu = sum * (1.0f / DIM);
    const float var = ssq * (1.0f / DIM) - mu * mu;
    const float rstd = rsqrtf(var + EPS);
    bf16* orow = h2 + base;
#pragma unroll
    for (int i = 0; i < 4; i++) {
        const int idx = tid + i * 256;
        orow[idx] = (bf16)((v[i] - mu) * rstd * g[idx] + b[idx]);
    }
}

// ---------------- final reducer: out += q0+q1+q2+q3 + fc2_b ----------------
__global__ __launch_bounds__(256) void add2_kernel(float* __restrict__ out,
                                                   const bf16* __restrict__ q0,
                                                   const bf16* __restrict__ q1,
                                                   const bf16* __restrict__ q2,
                                                   const bf16* __restrict__ q3,
                                                   const float* __restrict__ bias) {
    const size_t i = ((size_t)blockIdx.x * 256 + threadIdx.x) * 4;
    const int col = (int)(i & (DIM - 1));
    float4 o = *(const float4*)(out + i);
    const float4 bv = *(const float4*)(bias + col);
    bf16x4 a0 = *(const bf16x4*)(q0 + i);
    bf16x4 a1 = *(const bf16x4*)(q1 + i);
    bf16x4 a2 = *(const bf16x4*)(q2 + i);
    bf16x4 a3 = *(const bf16x4*)(q3 + i);
    o.x += (float)a0[0] + (float)a1[0] + (float)a2[0] + (float)a3[0] + bv.x;
    o.y += (float)a0[1] + (float)a1[1] + (float)a2[1] + (float)a3[1] + bv.y;
    o.z += (float)a0[2] + (float)a1[2] + (float)a2[2] + (float)a3[2] + bv.z;
    o.w += (float)a0[3] + (float)a1[3] + (float)a2[3] + (float)a3[3] + bv.w;
    *(float4*)(out + i) = o;
}

// ---------------- bf16 MFMA GEMM: BK=64 K-loop, XOR-swizzled LDS ----------------
// C[M,N] = A[M,K] @ W[N,K]^T. 128x128 tile, BK=64 (32 KB LDS), 4 waves = 64x64
// quadrants, 32 MFMA per barrier (halved drain count vs BK=32).
// LDS row-major [128][64] bf16 (128 B row = 32 banks); 16B chunk c of row r is
// stored at slot c^(r&7). Staging lane L of wave w covers row w*8+(L>>3)
// (+32 per shot s), slot L&7, fetching global chunk (L&7)^(L>>3).
// Fragment read row wm+fm+16t, k-chunk g+4ks -> slot (g+4ks)^(fm&7): the 8
// distinct fm&7 values spread across all 32 banks -> 2 lanes/bank (free).
#define ACT_NONE 0
#define ACT_GELU 1

template <int ACT, bool OUT_BF16, bool VT, int SPLITK>
__global__ __launch_bounds__(256) void mfma_gemm(const bf16* __restrict__ A,
                                                 const bf16* __restrict__ W,
                                                 const float* __restrict__ bias,
                                                 void* __restrict__ Cout,
                                                 bf16* __restrict__ vTout,
                                                 bf16* __restrict__ part,
                                                 int M, int N, int K) {
    __shared__ __align__(16) bf16 As[128 * 64];
    __shared__ __align__(16) bf16 Bs[128 * 64];

    const int tid = threadIdx.x;
    const int w = tid >> 6, lane = tid & 63;
    const int bm = blockIdx.y * 128, bn = blockIdx.x * 128;
    const int kseg = K / SPLITK;
    const int k0 = (SPLITK > 1) ? blockIdx.z * kseg : 0;

    // staging pointers: row = w*8 + (lane>>3) (+32/shot), global chunk (lane&7)^(lane>>3)
    const int srow = w * 8 + (lane >> 3);
    const int schunk = (lane & 7) ^ (lane >> 3);
    const bf16* pa = A + (size_t)(bm + srow) * K + k0 + schunk * 8;
    const bf16* pb = W + (size_t)(bn + srow) * K + k0 + schunk * 8;
    const size_t shotskip = (size_t)32 * K;
    char* ldsA = (char*)As + (w << 10);
    char* ldsB = (char*)Bs + (w << 10);

    const int wm = (w & 1) * 64, wn = (w >> 1) * 64;
    const int fm = lane & 15, g = lane >> 4;
    // fragment offsets (elements): row*64 + slot*8, slot = (g+4ks)^(fm&7)
    const int fr = fm * 64;
    const int sl0 = (g ^ (fm & 7)) * 8;
    const int sl1 = ((g + 4) ^ (fm & 7)) * 8;
    const bf16* aoff = As + (size_t)(wm * 64) + fr;
    const bf16* boff = Bs + (size_t)(wn * 64) + fr;

    f32x4 acc[4][4] = {};

    for (int kk = 0; kk < kseg; kk += 64) {
#pragma unroll
        for (int s = 0; s < 4; s++) {
            __builtin_amdgcn_global_load_lds((const AS1 void*)(pa + s * shotskip),
                                             (AS3 void*)(ldsA + s * 4096), 16, 0, 0);
            __builtin_amdgcn_global_load_lds((const AS1 void*)(pb + s * shotskip),
                                             (AS3 void*)(ldsB + s * 4096), 16, 0, 0);
        }
        pa += 64; pb += 64;
        __syncthreads();

#pragma unroll
        for (int ks = 0; ks < 2; ks++) {
            const int sl = ks ? sl1 : sl0;
            bf16x8 af[4], bfr[4];
#pragma unroll
            for (int t = 0; t < 4; t++) af[t] = *(const bf16x8*)(aoff + t * 1024 + sl);
#pragma unroll
            for (int t = 0; t < 4; t++) bfr[t] = *(const bf16x8*)(boff + t * 1024 + sl);
#pragma unroll
            for (int mt = 0; mt < 4; mt++)
#pragma unroll
                for (int nt = 0; nt < 4; nt++)
                    acc[mt][nt] = __builtin_amdgcn_mfma_f32_16x16x32_bf16(af[mt], bfr[nt], acc[mt][nt], 0, 0, 0);
        }
        __syncthreads();
    }

    // epilogue: D mapping col = lane&15, row = (lane>>4)*4 + reg
    const int cn = bn + wn + fm;
    const int rm = bm + wm + g * 4;

    if (SPLITK > 1) {
        bf16* pp = part + (size_t)blockIdx.z * M * N;
#pragma unroll
        for (int mt = 0; mt < 4; mt++) {
#pragma unroll
            for (int r = 0; r < 4; r++) {
                const size_t rowoff = (size_t)(rm + mt * 16 + r) * N;
#pragma unroll
                for (int nt = 0; nt < 4; nt++)
                    pp[rowoff + cn + nt * 16] = (bf16)acc[mt][nt][r];
            }
        }
        return;
    }

    float bv[4];
#pragma unroll
    for (int nt = 0; nt < 4; nt++) bv[nt] = bias[cn + nt * 16];

    if (VT && bn >= 2048) {
        const int dg0 = cn - 2048;
#pragma unroll
        for (int mt = 0; mt < 4; mt++) {
            const int mrow = rm + mt * 16;
            const int bI = mrow >> 10, j0 = mrow & 1023;
#pragma unroll
            for (int nt = 0; nt < 4; nt++) {
                const int dg = dg0 + nt * 16;
                bf16x4 v4 = {(bf16)(acc[mt][nt][0] + bv[nt]), (bf16)(acc[mt][nt][1] + bv[nt]),
                             (bf16)(acc[mt][nt][2] + bv[nt]), (bf16)(acc[mt][nt][3] + bv[nt])};
                *(bf16x4*)(vTout + ((size_t)(bI * 1024 + dg)) * 1024 + j0) = v4;
            }
        }
        return;
    }

#pragma unroll
    for (int mt = 0; mt < 4; mt++) {
#pragma unroll
        for (int r = 0; r < 4; r++) {
            const size_t rowoff = (size_t)(rm + mt * 16 + r) * N;
#pragma unroll
            for (int nt = 0; nt < 4; nt++) {
                float val = acc[mt][nt][r] + bv[nt];
                if (ACT == ACT_GELU) val = 0.5f * val * (1.0f + erff(val * 0.70710678118654752f));
                if (OUT_BF16) ((bf16*)Cout)[rowoff + cn + nt * 16] = (bf16)val;
                else          ((float*)Cout)[rowoff + cn + nt * 16] = val;
            }
        }
    }
}

// ---------------- MFMA flash attention (R4-proven) ----------------
__global__ __launch_bounds__(256) void fattn_mfma(const bf16* __restrict__ qkv,
                                                  const bf16* __restrict__ vT,
                                                  bf16* __restrict__ out) {
    __shared__ __align__(16) bf16 Ks[64 * 64];
    __shared__ __align__(16) bf16 Vt[64 * 64];
    __shared__ __align__(16) bf16 Ps[64 * 68];

    const int bid = blockIdx.x;
    const int qt = bid & 15;
    const int h = (bid >> 4) & 15;
    const int b = bid >> 8;
    const int tid = threadIdx.x;
    const int w = tid >> 6, lane = tid & 63;
    const int li = lane & 15, g = lane >> 4;

    bf16x8 aQ[2];
    {
        const size_t tok = (size_t)b * NSEQ + qt * 64 + w * 16 + li;
#pragma unroll
        for (int ks = 0; ks < 2; ks++)
            aQ[ks] = *(const bf16x8*)(qkv + tok * (3 * DIM) + h * HEAD_DIM + g * 8 + 32 * ks);
    }

    float mrun[4] = {-INFINITY, -INFINITY, -INFINITY, -INFINITY};
    float lrun[4] = {0.f, 0.f, 0.f, 0.f};
    f32x4 o[4] = {};

    const int idx0 = w * 128 + lane;
    const int idx1 = idx0 + 64;
    const int jl0 = idx0 >> 3, c0 = (idx0 & 7) ^ (jl0 & 7);
    const int jl1 = idx1 >> 3, c1 = (idx1 & 7) ^ (jl1 & 7);
    bf16* ldsK0 = Ks + (size_t)(w * 128) * 8;
    bf16* ldsK1 = Ks + (size_t)(w * 128 + 64) * 8;
    bf16* ldsV0 = Vt + (size_t)(w * 128) * 8;
    bf16* ldsV1 = Vt + (size_t)(w * 128 + 64) * 8;
    const bf16* kbase = qkv + (size_t)b * NSEQ * (3 * DIM) + DIM + h * HEAD_DIM;
    const bf16* vbase = vT + ((size_t)b * DIM + h * HEAD_DIM) * NSEQ;

    for (int k0 = 0; k0 < NSEQ; k0 += 64) {
        __syncthreads();
        __builtin_amdgcn_global_load_lds((const AS1 void*)(kbase + (size_t)(k0 + jl0) * (3 * DIM) + c0 * 8),
                                         (AS3 void*)ldsK0, 16, 0, 0);
        __builtin_amdgcn_global_load_lds((const AS1 void*)(kbase + (size_t)(k0 + jl1) * (3 * DIM) + c1 * 8),
                                         (AS3 void*)ldsK1, 16, 0, 0);
        __builtin_amdgcn_global_load_lds((const AS1 void*)(vbase + (size_t)jl0 * NSEQ + k0 + c0 * 8),
                                         (AS3 void*)ldsV0, 16, 0, 0);
        __builtin_amdgcn_global_load_lds((const AS1 void*)(vbase + (size_t)jl1 * NSEQ + k0 + c1 * 8),
                                         (AS3 void*)ldsV1, 16, 0, 0);
        __syncthreads();

        f32x4 s[4] = {};
#pragma unroll
        for (int ks = 0; ks < 2; ks++) {
#pragma unroll
            for (int nt = 0; nt < 4; nt++) {
                const int j = li + 16 * nt;
                const int p = (g + 4 * ks) ^ (j & 7);
                bf16x8 bK = *(const bf16x8*)(Ks + j * 64 + p * 8);
                s[nt] = __builtin_amdgcn_mfma_f32_16x16x32_bf16(aQ[ks], bK, s[nt], 0, 0, 0);
            }
        }
#pragma unroll
        for (int nt = 0; nt < 4; nt++) s[nt] *= 0.125f;

        float m4[4], rs[4], alpha[4];
#pragma unroll
        for (int r = 0; r < 4; r++)
            m4[r] = fmaxf(fmaxf(s[0][r], s[1][r]), fmaxf(s[2][r], s[3][r]));
#pragma unroll
        for (int mask = 1; mask < 16; mask <<= 1)
#pragma unroll
            for (int r = 0; r < 4; r++) m4[r] = fmaxf(m4[r], __shfl_xor(m4[r], mask, 64));
#pragma unroll
        for (int r = 0; r < 4; r++) {
            const float mn = fmaxf(mrun[r], m4[r]);
            alpha[r] = __expf(mrun[r] - mn);
            mrun[r] = mn;
        }
#pragma unroll
        for (int r = 0; r < 4; r++) rs[r] = 0.f;
#pragma unroll
        for (int nt = 0; nt < 4; nt++) {
#pragma unroll
            for (int r = 0; r < 4; r++) {
                const float p = __expf(s[nt][r] - mrun[r]);
                rs[r] += p;
                Ps[(w * 16 + g * 4 + r) * 68 + li + 16 * nt] = (bf16)p;
            }
        }
#pragma unroll
        for (int mask = 1; mask < 16; mask <<= 1)
#pragma unroll
            for (int r = 0; r < 4; r++) rs[r] += __shfl_xor(rs[r], mask, 64);
#pragma unroll
        for (int r = 0; r < 4; r++) lrun[r] = lrun[r] * alpha[r] + rs[r];
#pragma unroll
        for (int nt = 0; nt < 4; nt++)
#pragma unroll
            for (int r = 0; r < 4; r++) o[nt][r] *= alpha[r];

        bf16x8 aP[2];
#pragma unroll
        for (int ks = 0; ks < 2; ks++) {
            const int off = (w * 16 + li) * 68 + g * 8 + 32 * ks;
            bf16x4 lo = *(const bf16x4*)(Ps + off);
            bf16x4 hi = *(const bf16x4*)(Ps + off + 4);
            aP[ks] = bf16x8{lo[0], lo[1], lo[2], lo[3], hi[0], hi[1], hi[2], hi[3]};
        }
#pragma unroll
        for (int ks = 0; ks < 2; ks++) {
#pragma unroll
            for (int nt = 0; nt < 4; nt++) {
                const int d = li + 16 * nt;
                const int p = (g + 4 * ks) ^ (d & 7);
                bf16x8 bV = *(const bf16x8*)(Vt + d * 64 + p * 8);
                o[nt] = __builtin_amdgcn_mfma_f32_16x16x32_bf16(aP[ks], bV, o[nt], 0, 0, 0);
            }
        }
    }

    float linv[4];
#pragma unroll
    for (int r = 0; r < 4; r++) linv[r] = 1.0f / lrun[r];
    const size_t tok0 = (size_t)b * NSEQ + qt * 64 + w * 16 + g * 4;
#pragma unroll
    for (int r = 0; r < 4; r++) {
#pragma unroll
        for (int nt = 0; nt < 4; nt++)
            out[(tok0 + r) * DIM + h * HEAD_DIM + 16 * nt + li] = (bf16)(o[nt][r] * linv[r]);
    }
}

// ---------------- launch ----------------
extern "C" void kernel_launch(void* const* d_in, const int* in_sizes, int n_in,
                              void* d_out, int out_size, void* d_ws, size_t ws_size,
                              hipStream_t stream) {
    const float* x      = (const float*)d_in[0];
    const float* ln1_g  = (const float*)d_in[1];
    const float* ln1_b  = (const float*)d_in[2];
    const float* qkv_w  = (const float*)d_in[3];
    const float* qkv_b  = (const float*)d_in[4];
    const float* proj_w = (const float*)d_in[5];
    const float* proj_b = (const float*)d_in[6];
    const float* ln2_g  = (const float*)d_in[7];
    const float* ln2_b  = (const float*)d_in[8];
    const float* fc1_w  = (const float*)d_in[9];
    const float* fc1_b  = (const float*)d_in[10];
    const float* fc2_w  = (const float*)d_in[11];
    const float* fc2_b  = (const float*)d_in[12];
    float* out = (float*)d_out;

    char* p = (char*)d_ws;
    bf16*  h_bf    = (bf16*)p;  p += (size_t)TOKENS * DIM * 2;         // 8MB
    bf16*  attn_bf = (bf16*)p;  p += (size_t)TOKENS * DIM * 2;         // 8MB
    bf16*  ffn_bf  = (bf16*)p;  p += (size_t)TOKENS * HIDDEN * 2;      // 32MB
    bf16*  qkv_bf  = (bf16*)p;  p += (size_t)TOKENS * 3 * DIM * 2;     // 24MB (dead after fattn)
    bf16*  vT_bf   = (bf16*)p;  p += (size_t)BATCH * DIM * NSEQ * 2;   // 8MB  (dead after fattn)
    bf16*  wq_bf   = (bf16*)p;  p += (size_t)3 * DIM * DIM * 2;
    bf16*  wp_bf   = (bf16*)p;  p += (size_t)DIM * DIM * 2;
    bf16*  w1_bf   = (bf16*)p;  p += (size_t)HIDDEN * DIM * 2;
    bf16*  w2_bf   = (bf16*)p;  p += (size_t)DIM * HIDDEN * 2;
    bf16*  proj_part = qkv_bf;   // 2 x 8MB overlay on dead qkv/vT region
    bf16*  fc2_part  = qkv_bf;   // 4 x 8MB

    // 0) fused weight convert + LN1
    prep_kernel<<<CVT_BLOCKS + TOKENS, 256, 0, stream>>>(
        x, ln1_g, ln1_b, h_bf, qkv_w, proj_w, fc1_w, fc2_w, wq_bf, wp_bf, w1_bf, w2_bf);
    // 1) qkv = h @ qkv_w^T + b -> bf16 (Q,K) + transposed V -> vT_bf
    mfma_gemm<ACT_NONE, true, true, 1><<<dim3(3 * DIM / 128, TOKENS / 128), 256, 0, stream>>>(
        h_bf, wq_bf, qkv_b, qkv_bf, vT_bf, nullptr, TOKENS, 3 * DIM, DIM);
    // 2) MFMA flash attention -> bf16
    fattn_mfma<<<BATCH * HEADS * (NSEQ / 64), 256, 0, stream>>>(qkv_bf, vT_bf, attn_bf);
    // 3) proj partials (split-K 2, bf16 stores)
    mfma_gemm<ACT_NONE, false, false, 2><<<dim3(DIM / 128, TOKENS / 128, 2), 256, 0, stream>>>(
        attn_bf, wp_bf, proj_b, nullptr, nullptr, proj_part, TOKENS, DIM, DIM);
    // 4) x1 = x + p0 + p1 + proj_b -> out; h2 = LN2(x1) -> bf16
    ln2add_kernel<<<TOKENS, 256, 0, stream>>>(
        x, proj_part, proj_part + (size_t)TOKENS * DIM, proj_b, ln2_g, ln2_b, out, h_bf);
    // 5) ffn = gelu(h2 @ fc1_w^T + b) -> bf16
    mfma_gemm<ACT_GELU, true, false, 1><<<dim3(HIDDEN / 128, TOKENS / 128), 256, 0, stream>>>(
        h_bf, w1_bf, fc1_b, ffn_bf, nullptr, nullptr, TOKENS, HIDDEN, DIM);
    // 6) fc2 partials (split-K 4, bf16 stores)
    mfma_gemm<ACT_NONE, false, false, 4><<<dim3(DIM / 128, TOKENS / 128, 4), 256, 0, stream>>>(
        ffn_bf, w2_bf, fc2_b, nullptr, nullptr, fc2_part, TOKENS, DIM, HIDDEN);
    // 7) out = x1 + q0+q1+q2+q3 + fc2_b
    add2_kernel<<<TOKENS * DIM / 1024, 256, 0, stream>>>(
        out, fc2_part, fc2_part + (size_t)TOKENS * DIM, fc2_part + (size_t)2 * TOKENS * DIM,
        fc2_part + (size_t)3 * TOKENS * DIM, fc2_b);
}